// Round 26
// baseline (204.405 us; speedup 1.0000x reference)
//
#include <hip/hip_runtime.h>
#include <hip/hip_bf16.h>

// FlowNetC correlation, round 26: prepack + barrier-free band-only MFMA, 3 dyi/block.
// r25: 146us, L2 ~17.7 TB/s, VGPR=56 (prefetch folded), 1 MFMA per 1KB load ->
// latency/traffic bound. Merge 3 dyi (r22 decode): A fragment pair feeds 15 MFMAs
// per chunk (was 5), per-block reads 480->352KB per dyi-triple (-27% total L2 traffic).

typedef __attribute__((ext_vector_type(8))) short bf16x8;
typedef __attribute__((ext_vector_type(4))) float f32x4;
typedef __attribute__((ext_vector_type(4))) unsigned u32x4;

constexpr int Bn = 8, Cn = 256, Hn = 96, Wn = 128, GW = 21;
constexpr int KC = 32, NCH = Cn / KC;     // 8 chunks of 32 channels
constexpr int NDG = 7;                    // dyi triples (21 = 3*7)
constexpr int NWG3 = Bn * Hn * NDG;       // 5376, divisible by 8
constexpr int NWGFB = Bn * Hn * GW;       // fallback grid
constexpr int JW = 23;                    // sout pad
constexpr size_t TELEMS = (size_t)Bn * Hn * NCH * 2048;  // 12,582,912 u32 per input

__device__ inline unsigned pack_bf16(float lo, float hi) {
    __hip_bfloat16 l = __float2bfloat16(lo);
    __hip_bfloat16 h = __float2bfloat16(hi);
    unsigned short lu, hu;
    __builtin_memcpy(&lu, &l, 2);
    __builtin_memcpy(&hu, &h, 2);
    return (unsigned)lu | ((unsigned)hu << 16);
}

// ---------------- prepack: f32 -> bf16-pair u32 panels (r24, proven) ----------------
// T[inp][b][y][chunk][par][mt4][kg4][pos16][ku4]; u32 = {bf16(c), bf16(c+1)},
// c = chunk*32 + 8*kg + 2*ku, x = 2*(mt*16+pos)+par.
__global__ __launch_bounds__(256) void prepack(
    const float* __restrict__ in1, const float* __restrict__ in2,
    unsigned* __restrict__ T)
{
    unsigned u = blockIdx.x;
    int ch = u & 7;  u >>= 3;
    int y  = u % 96; u /= 96;
    int b  = u & 7;  u >>= 3;
    const float* src = u ? in2 : in1;

    int t  = threadIdx.x;
    int tm = t & 63;          // x-pair
    int tg = t >> 6;          // kg

    const size_t chw = (size_t)Hn * Wn;
    const float* p = src + ((size_t)(b * Cn + ch * 32 + 8 * tg)) * chw
                         + (size_t)y * Wn + 2 * tm;
    float2 f[8];
#pragma unroll
    for (int k = 0; k < 8; ++k)
        f[k] = *(const float2*)(p + (size_t)k * chw);

    u32x4 ae, ao;
#pragma unroll
    for (int ku = 0; ku < 4; ++ku) {
        ae[ku] = pack_bf16(f[2 * ku].x, f[2 * ku + 1].x);
        ao[ku] = pack_bf16(f[2 * ku].y, f[2 * ku + 1].y);
    }
    unsigned* To = T + u * TELEMS + ((size_t)(b * Hn + y) * NCH + ch) * 2048
                     + ((tm >> 4) * 4 + tg) * 64 + (tm & 15) * 4;
    *(u32x4*)(To)        = ae;    // par 0
    *(u32x4*)(To + 1024) = ao;    // par 1
}

// ---------------- main: barrier-free band-only MFMA Gram, 3 dyi/block ----------------
__global__ __launch_bounds__(256) void corr_frag3(
    const unsigned* __restrict__ T1, const unsigned* __restrict__ T2,
    float* __restrict__ out)
{
    __shared__ float sout[Wn * JW];   // 11.5 KB, epilogue only

    // r22 L2-locality decode: XCD owns y-band of 12; (b, par, sub, dg, yw)
    int orig = blockIdx.x;
    int xcd  = orig & 7;
    int i    = orig >> 3;            // 0..671
    int yw   = i % 3;  int t = i / 3;
    int dg   = t % NDG; t /= NDG;    // t in [0,32)
    int sub  = t & 1;
    int par  = (t >> 1) & 1;
    int b    = t >> 2;
    int y    = 12 * xcd + par + 2 * (3 * sub + yw);

    int rowv[3], y2c[3];
#pragma unroll
    for (int d = 0; d < 3; ++d) {
        int y2 = y + 2 * (3 * dg + d) - 20;
        rowv[d] = (y2 >= 0) && (y2 < Hn);
        y2c[d]  = rowv[d] ? y2 : 0;
    }

    int tid = threadIdx.x;
    int w   = tid >> 6;          // wave 0..3
    int l   = tid & 63;
    int p   = w >> 1;            // parity
    int h   = w & 1;             // x-half: mt in {2h, 2h+1}
    int g   = l >> 4;            // k-group
    int m16 = l & 15;

    f32x4 acc[3][2][4] = {};     // acc[d][a][n]; only band entries touched in loop

    {
        const unsigned* pa = T1 + (size_t)(b * Hn + y) * (NCH * 2048)
                                + p * 1024 + g * 64 + m16 * 4;
        const unsigned* pb0 = T2 + (size_t)(b * Hn + y2c[0]) * (NCH * 2048)
                                 + p * 1024 + g * 64 + m16 * 4 + h * 256;
        const unsigned* pb1 = T2 + (size_t)(b * Hn + y2c[1]) * (NCH * 2048)
                                 + p * 1024 + g * 64 + m16 * 4 + h * 256;
        const unsigned* pb2 = T2 + (size_t)(b * Hn + y2c[2]) * (NCH * 2048)
                                 + p * 1024 + g * 64 + m16 * 4 + h * 256;

        for (int ch = 0; ch < NCH; ++ch) {
            const unsigned* A = pa + ch * 2048;
            bf16x8 a0 = *(const bf16x8*)(A + (2 * h + 0) * 256);
            bf16x8 a1 = *(const bf16x8*)(A + (2 * h + 1) * 256);
#pragma unroll
            for (int d = 0; d < 3; ++d) {
                const unsigned* B = (d == 0 ? pb0 : (d == 1 ? pb1 : pb2)) + ch * 2048;
                bf16x8 b0 = *(const bf16x8*)(B + 0 * 256);
                bf16x8 b1 = *(const bf16x8*)(B + 1 * 256);
                bf16x8 b2 = *(const bf16x8*)(B + 2 * 256);
                if (h == 0) {
                    // mt=0: nt 0,1; mt=1: nt 0,1,2  (b_k = row k)
                    acc[d][0][0] = __builtin_amdgcn_mfma_f32_16x16x32_bf16(a0, b0, acc[d][0][0], 0, 0, 0);
                    acc[d][0][1] = __builtin_amdgcn_mfma_f32_16x16x32_bf16(a0, b1, acc[d][0][1], 0, 0, 0);
                    acc[d][1][0] = __builtin_amdgcn_mfma_f32_16x16x32_bf16(a1, b0, acc[d][1][0], 0, 0, 0);
                    acc[d][1][1] = __builtin_amdgcn_mfma_f32_16x16x32_bf16(a1, b1, acc[d][1][1], 0, 0, 0);
                    acc[d][1][2] = __builtin_amdgcn_mfma_f32_16x16x32_bf16(a1, b2, acc[d][1][2], 0, 0, 0);
                } else {
                    // mt=2: nt 1,2,3 (b_k = row 1+k); mt=3: nt 2,3
                    acc[d][0][1] = __builtin_amdgcn_mfma_f32_16x16x32_bf16(a0, b0, acc[d][0][1], 0, 0, 0);
                    acc[d][0][2] = __builtin_amdgcn_mfma_f32_16x16x32_bf16(a0, b1, acc[d][0][2], 0, 0, 0);
                    acc[d][0][3] = __builtin_amdgcn_mfma_f32_16x16x32_bf16(a0, b2, acc[d][0][3], 0, 0, 0);
                    acc[d][1][2] = __builtin_amdgcn_mfma_f32_16x16x32_bf16(a1, b1, acc[d][1][2], 0, 0, 0);
                    acc[d][1][3] = __builtin_amdgcn_mfma_f32_16x16x32_bf16(a1, b2, acc[d][1][3], 0, 0, 0);
                }
            }
        }
    }

    // ---- epilogue: 3 planes, LDS-transposed coalesced stores (r22, proven) ----
    const float scale = 1.0f / 256.0f;
    constexpr unsigned PLANE = (unsigned)(Hn * Wn);

#pragma unroll
    for (int d = 0; d < 3; ++d) {
        __syncthreads();                   // previous plane's reads done
        for (int i2 = tid; i2 < Wn * JW; i2 += 256) sout[i2] = 0.0f;
        __syncthreads();                   // zeros visible
        if (rowv[d]) {
#pragma unroll
            for (int a = 0; a < 2; ++a)
#pragma unroll
                for (int n = 0; n < 4; ++n)
#pragma unroll
                    for (int r = 0; r < 4; ++r) {
                        int xp = (2 * h + a) * 16 + g * 4 + r;   // x' (C/D row)
                        int up = n * 16 + m16;                   // u' (C/D col)
                        int j  = up - xp + 10;
                        if ((unsigned)j < 21u)
                            sout[(2 * xp + p) * JW + j] = acc[d][a][n][r] * scale;
                    }
        }
        __syncthreads();                   // scatter visible
        unsigned base0 = (unsigned)(((b * (GW * GW) + (3 * dg + d) * GW) * Hn + y) * Wn);
        for (int s = tid; s < GW * Wn; s += 256) {
            int j = s >> 7;
            int x = s & 127;
            out[base0 + (unsigned)j * PLANE + (unsigned)x] = sout[x * JW + j];
        }
    }
}

// ---------------- fallback (r21, proven): used if ws too small ----------------
__device__ inline void lds_barrier() {
    asm volatile("s_waitcnt lgkmcnt(0)" ::: "memory");
    __builtin_amdgcn_s_barrier();
    __builtin_amdgcn_sched_barrier(0);
}

__global__ __launch_bounds__(256) void corr_mfma_fb(
    const float* __restrict__ in1, const float* __restrict__ in2,
    float* __restrict__ out)
{
    __shared__ unsigned lds[4][1024];
    int orig = blockIdx.x;
    int xcd  = orig & 7;
    int i    = orig >> 3;
    int yw   = i % 3;  int t = i / 3;
    int dyi  = t % 21; t /= 21;
    int sub  = t & 1;
    int par  = (t >> 1) & 1;
    int b    = t >> 2;
    int y    = 12 * xcd + par + 2 * (3 * sub + yw);
    int y2  = y + 2 * dyi - 20;
    bool y2ok = (y2 >= 0) && (y2 < Hn);

    int tid = threadIdx.x;
    int w   = tid >> 6;
    int l   = tid & 63;
    int p   = w >> 1;
    int h   = w & 1;
    int g   = l >> 4;
    int m16 = l & 15;

    const size_t chw = (size_t)Hn * Wn;
    const float* pA = in1 + ((size_t)b * Cn) * chw + (size_t)y * Wn;
    const float* pB = in2 + ((size_t)b * Cn) * chw + (size_t)(y2ok ? y2 : 0) * Wn;

    int tm = tid & 63;
    int tg = tid >> 6;
    const int loff = ((tm >> 4) * 4 + tg) * 64 + (tm & 15) * 4;

    f32x4 acc[2][4] = {};
    float ax[8], ay[8], bx[8], by[8];

    auto prefetch = [&](int chunk) {
        size_t base = (size_t)(chunk * KC + 8 * tg) * chw + 2 * tm;
#pragma unroll
        for (int k = 0; k < 8; ++k) {
            float2 tA = *(const float2*)(pA + base + (size_t)k * chw);
            float2 tB = *(const float2*)(pB + base + (size_t)k * chw);
            ax[k] = tA.x; ay[k] = tA.y;
            bx[k] = tB.x; by[k] = tB.y;
        }
        __builtin_amdgcn_sched_barrier(0);
    };
    auto writeout = [&]() {
#pragma unroll
        for (int k = 0; k < 8; ++k)
            asm volatile("" : "+v"(ax[k]), "+v"(ay[k]), "+v"(bx[k]), "+v"(by[k]));
        u32x4 ae, ao, be, bo;
#pragma unroll
        for (int ku = 0; ku < 4; ++ku) {
            ae[ku] = pack_bf16(ax[2 * ku], ax[2 * ku + 1]);
            ao[ku] = pack_bf16(ay[2 * ku], ay[2 * ku + 1]);
            be[ku] = pack_bf16(bx[2 * ku], bx[2 * ku + 1]);
            bo[ku] = pack_bf16(by[2 * ku], by[2 * ku + 1]);
        }
        *(u32x4*)&lds[0][loff] = ae;
        *(u32x4*)&lds[1][loff] = ao;
        *(u32x4*)&lds[2][loff] = be;
        *(u32x4*)&lds[3][loff] = bo;
    };
    auto compute = [&]() {
        const unsigned* Pa = &lds[p][0];
        const unsigned* Pb = &lds[2 + p][0];
        int fo = g * 64 + m16 * 4;
        bf16x8 A0  = *(const bf16x8*)(Pa + (2 * h + 0) * 256 + fo);
        bf16x8 A1  = *(const bf16x8*)(Pa + (2 * h + 1) * 256 + fo);
        bf16x8 Bf0 = *(const bf16x8*)(Pb + 0 * 256 + fo);
        bf16x8 Bf1 = *(const bf16x8*)(Pb + 1 * 256 + fo);
        bf16x8 Bf2 = *(const bf16x8*)(Pb + 2 * 256 + fo);
        bf16x8 Bf3 = *(const bf16x8*)(Pb + 3 * 256 + fo);
        acc[0][0] = __builtin_amdgcn_mfma_f32_16x16x32_bf16(A0, Bf0, acc[0][0], 0, 0, 0);
        acc[0][1] = __builtin_amdgcn_mfma_f32_16x16x32_bf16(A0, Bf1, acc[0][1], 0, 0, 0);
        acc[0][2] = __builtin_amdgcn_mfma_f32_16x16x32_bf16(A0, Bf2, acc[0][2], 0, 0, 0);
        acc[0][3] = __builtin_amdgcn_mfma_f32_16x16x32_bf16(A0, Bf3, acc[0][3], 0, 0, 0);
        acc[1][0] = __builtin_amdgcn_mfma_f32_16x16x32_bf16(A1, Bf0, acc[1][0], 0, 0, 0);
        acc[1][1] = __builtin_amdgcn_mfma_f32_16x16x32_bf16(A1, Bf1, acc[1][1], 0, 0, 0);
        acc[1][2] = __builtin_amdgcn_mfma_f32_16x16x32_bf16(A1, Bf2, acc[1][2], 0, 0, 0);
        acc[1][3] = __builtin_amdgcn_mfma_f32_16x16x32_bf16(A1, Bf3, acc[1][3], 0, 0, 0);
    };

    if (y2ok) {
        prefetch(0);
        for (int it = 0; it < NCH; ++it) {
            writeout();
            lds_barrier();
            if (it + 1 < NCH) prefetch(it + 1);
            compute();
            lds_barrier();
        }
    }

    __syncthreads();
    float* sout = (float*)&lds[0][0];
    for (int i2 = tid; i2 < Wn * JW; i2 += 256) sout[i2] = 0.0f;
    __syncthreads();
    if (y2ok) {
        const float scale = 1.0f / 256.0f;
#pragma unroll
        for (int a = 0; a < 2; ++a)
#pragma unroll
            for (int n = 0; n < 4; ++n)
#pragma unroll
                for (int r = 0; r < 4; ++r) {
                    int xp = (2 * h + a) * 16 + g * 4 + r;
                    int up = n * 16 + m16;
                    int j  = up - xp + 10;
                    if ((unsigned)j < 21u)
                        sout[(2 * xp + p) * JW + j] = acc[a][n][r] * scale;
                }
    }
    __syncthreads();
    unsigned base0 = (unsigned)(((b * (GW * GW) + dyi * GW) * Hn + y) * Wn);
    constexpr unsigned PLANE = (unsigned)(Hn * Wn);
    for (int s = tid; s < GW * Wn; s += 256) {
        int j = s >> 7;
        int x = s & 127;
        out[base0 + (unsigned)j * PLANE + (unsigned)x] = sout[x * JW + j];
    }
}

extern "C" void kernel_launch(void* const* d_in, const int* in_sizes, int n_in,
                              void* d_out, int out_size, void* d_ws, size_t ws_size,
                              hipStream_t stream) {
    const float* in1 = (const float*)d_in[0];
    const float* in2 = (const float*)d_in[1];
    float* out = (float*)d_out;
    size_t need = 2 * TELEMS * sizeof(unsigned);   // 100,663,296 B
    if (ws_size >= need) {
        unsigned* T = (unsigned*)d_ws;
        prepack<<<2 * Bn * Hn * NCH, 256, 0, stream>>>(in1, in2, T);
        corr_frag3<<<NWG3, 256, 0, stream>>>(T, T + TELEMS, out);
    } else {
        corr_mfma_fb<<<NWGFB, 256, 0, stream>>>(in1, in2, out);
    }
}

// Round 27
// 178.166 us; speedup vs baseline: 1.1473x; 1.1473x over previous
//
#include <hip/hip_runtime.h>
#include <hip/hip_bf16.h>

// FlowNetC correlation, round 27: prepack + barrier-free band MFMA, K-SPLIT waves.
// r24-r26 lesson: delivered L2 BW ~ occupancy x const-per-wave rate; r26's dyi-merge
// lost occupancy (VGPR 116) and regressed. New split: wave (p,h) = parity x CHANNEL
// half (chunks h,h+2,..). Each wave computes all 10 band tiles for its chunks:
// A rows 0-3 + B rows 0-3 per chunk -> ZERO B duplication (20->16 KB/chunk/block,
// -20%), 10 MFMA per 8 KB (+25% density), acc 40 VGPR (occupancy preserved).
// k-half partial sums combined in the epilogue via sout[2] + add at store.

typedef __attribute__((ext_vector_type(8))) short bf16x8;
typedef __attribute__((ext_vector_type(4))) float f32x4;
typedef __attribute__((ext_vector_type(4))) unsigned u32x4;

constexpr int Bn = 8, Cn = 256, Hn = 96, Wn = 128, GW = 21;
constexpr int KC = 32, NCH = Cn / KC;     // 8 chunks of 32 channels
constexpr int NWG = Bn * Hn * GW;         // 16128, divisible by 8
constexpr int JW = 23;                    // sout pad
constexpr size_t TELEMS = (size_t)Bn * Hn * NCH * 2048;  // 12,582,912 u32 per input

__device__ inline unsigned pack_bf16(float lo, float hi) {
    __hip_bfloat16 l = __float2bfloat16(lo);
    __hip_bfloat16 h = __float2bfloat16(hi);
    unsigned short lu, hu;
    __builtin_memcpy(&lu, &l, 2);
    __builtin_memcpy(&hu, &h, 2);
    return (unsigned)lu | ((unsigned)hu << 16);
}

// ---------------- prepack: f32 -> bf16-pair u32 panels (r24, proven) ----------------
// T[inp][b][y][chunk][par][mt4][kg4][pos16][ku4]; u32 = {bf16(c), bf16(c+1)},
// c = chunk*32 + 8*kg + 2*ku, x = 2*(mt*16+pos)+par.
__global__ __launch_bounds__(256) void prepack(
    const float* __restrict__ in1, const float* __restrict__ in2,
    unsigned* __restrict__ T)
{
    unsigned u = blockIdx.x;
    int ch = u & 7;  u >>= 3;
    int y  = u % 96; u /= 96;
    int b  = u & 7;  u >>= 3;
    const float* src = u ? in2 : in1;

    int t  = threadIdx.x;
    int tm = t & 63;          // x-pair
    int tg = t >> 6;          // kg

    const size_t chw = (size_t)Hn * Wn;
    const float* p = src + ((size_t)(b * Cn + ch * 32 + 8 * tg)) * chw
                         + (size_t)y * Wn + 2 * tm;
    float2 f[8];
#pragma unroll
    for (int k = 0; k < 8; ++k)
        f[k] = *(const float2*)(p + (size_t)k * chw);

    u32x4 ae, ao;
#pragma unroll
    for (int ku = 0; ku < 4; ++ku) {
        ae[ku] = pack_bf16(f[2 * ku].x, f[2 * ku + 1].x);
        ao[ku] = pack_bf16(f[2 * ku].y, f[2 * ku + 1].y);
    }
    unsigned* To = T + u * TELEMS + ((size_t)(b * Hn + y) * NCH + ch) * 2048
                     + ((tm >> 4) * 4 + tg) * 64 + (tm & 15) * 4;
    *(u32x4*)(To)        = ae;    // par 0
    *(u32x4*)(To + 1024) = ao;    // par 1
}

// ---------------- main: barrier-free band MFMA, k-split waves ----------------
__global__ __launch_bounds__(256) void corr_fragk(
    const unsigned* __restrict__ T1, const unsigned* __restrict__ T2,
    float* __restrict__ out)
{
    __shared__ float sout[2][Wn * JW];   // one partial-sum tile per k-half (23.5 KB)

    // r19 L2-locality decode: XCD owns y-band of 12; (b, par, sub, dyi, yw)
    int orig = blockIdx.x;
    int xcd  = orig & 7;
    int i    = orig >> 3;
    int yw   = i % 3;  int t = i / 3;
    int dyi  = t % 21; t /= 21;
    int sub  = t & 1;
    int par  = (t >> 1) & 1;
    int b    = t >> 2;
    int y    = 12 * xcd + par + 2 * (3 * sub + yw);

    int y2  = y + 2 * dyi - 20;
    bool y2ok = (y2 >= 0) && (y2 < Hn);

    int tid = threadIdx.x;
    int w   = tid >> 6;          // wave 0..3
    int l   = tid & 63;
    int p   = w >> 1;            // parity
    int h   = w & 1;             // CHANNEL half: chunks h, h+2, h+4, h+6
    int g   = l >> 4;            // k-group
    int m16 = l & 15;

    // band tiles: t0..t9 -> (mt,nt) with |nt-mt|<=1
    f32x4 acc[10] = {};

    if (y2ok) {
        const unsigned* pa = T1 + (size_t)(b * Hn + y)  * (NCH * 2048)
                                + p * 1024 + g * 64 + m16 * 4 + (size_t)h * 2048;
        const unsigned* pb = T2 + (size_t)(b * Hn + y2) * (NCH * 2048)
                                + p * 1024 + g * 64 + m16 * 4 + (size_t)h * 2048;

        for (int ch = 0; ch < NCH / 2; ++ch) {           // chunks h + 2*ch
            const unsigned* A = pa + (size_t)ch * 4096;
            const unsigned* B = pb + (size_t)ch * 4096;
            bf16x8 a0 = *(const bf16x8*)(A + 0 * 256);
            bf16x8 a1 = *(const bf16x8*)(A + 1 * 256);
            bf16x8 a2 = *(const bf16x8*)(A + 2 * 256);
            bf16x8 a3 = *(const bf16x8*)(A + 3 * 256);
            bf16x8 b0 = *(const bf16x8*)(B + 0 * 256);
            bf16x8 b1 = *(const bf16x8*)(B + 1 * 256);
            bf16x8 b2 = *(const bf16x8*)(B + 2 * 256);
            bf16x8 b3 = *(const bf16x8*)(B + 3 * 256);
            acc[0] = __builtin_amdgcn_mfma_f32_16x16x32_bf16(a0, b0, acc[0], 0, 0, 0); // (0,0)
            acc[1] = __builtin_amdgcn_mfma_f32_16x16x32_bf16(a0, b1, acc[1], 0, 0, 0); // (0,1)
            acc[2] = __builtin_amdgcn_mfma_f32_16x16x32_bf16(a1, b0, acc[2], 0, 0, 0); // (1,0)
            acc[3] = __builtin_amdgcn_mfma_f32_16x16x32_bf16(a1, b1, acc[3], 0, 0, 0); // (1,1)
            acc[4] = __builtin_amdgcn_mfma_f32_16x16x32_bf16(a1, b2, acc[4], 0, 0, 0); // (1,2)
            acc[5] = __builtin_amdgcn_mfma_f32_16x16x32_bf16(a2, b1, acc[5], 0, 0, 0); // (2,1)
            acc[6] = __builtin_amdgcn_mfma_f32_16x16x32_bf16(a2, b2, acc[6], 0, 0, 0); // (2,2)
            acc[7] = __builtin_amdgcn_mfma_f32_16x16x32_bf16(a2, b3, acc[7], 0, 0, 0); // (2,3)
            acc[8] = __builtin_amdgcn_mfma_f32_16x16x32_bf16(a3, b2, acc[8], 0, 0, 0); // (3,2)
            acc[9] = __builtin_amdgcn_mfma_f32_16x16x32_bf16(a3, b3, acc[9], 0, 0, 0); // (3,3)
        }
    }

    // ---- epilogue: per-h partial tiles, scatter, add at store ----
    for (int i2 = tid; i2 < 2 * Wn * JW; i2 += 256) (&sout[0][0])[i2] = 0.0f;
    __syncthreads();                       // zeros visible

    if (y2ok) {
        const float scale = 1.0f / 256.0f;
        const int mtT[10] = {0,0,1,1,1,2,2,2,3,3};
        const int ntT[10] = {0,1,0,1,2,1,2,3,2,3};
#pragma unroll
        for (int tt = 0; tt < 10; ++tt)
#pragma unroll
            for (int r = 0; r < 4; ++r) {
                int xp = mtT[tt] * 16 + g * 4 + r;       // x' (C/D row)
                int up = ntT[tt] * 16 + m16;             // u' (C/D col)
                int j  = up - xp + 10;
                if ((unsigned)j < 21u)
                    sout[h][(2 * xp + p) * JW + j] = acc[tt][r] * scale;
            }
    }
    __syncthreads();                       // scatter visible

    unsigned base0 = (unsigned)(((b * (GW * GW) + dyi * GW) * Hn + y) * Wn);
    constexpr unsigned PLANE = (unsigned)(Hn * Wn);
    for (int s = tid; s < GW * Wn; s += 256) {
        int j = s >> 7;
        int x = s & 127;
        out[base0 + (unsigned)j * PLANE + (unsigned)x] =
            sout[0][x * JW + j] + sout[1][x * JW + j];
    }
}

// ---------------- fallback (r21, proven): used if ws too small ----------------
__device__ inline void lds_barrier() {
    asm volatile("s_waitcnt lgkmcnt(0)" ::: "memory");
    __builtin_amdgcn_s_barrier();
    __builtin_amdgcn_sched_barrier(0);
}

__global__ __launch_bounds__(256) void corr_mfma_fb(
    const float* __restrict__ in1, const float* __restrict__ in2,
    float* __restrict__ out)
{
    __shared__ unsigned lds[4][1024];
    int orig = blockIdx.x;
    int xcd  = orig & 7;
    int i    = orig >> 3;
    int yw   = i % 3;  int t = i / 3;
    int dyi  = t % 21; t /= 21;
    int sub  = t & 1;
    int par  = (t >> 1) & 1;
    int b    = t >> 2;
    int y    = 12 * xcd + par + 2 * (3 * sub + yw);
    int y2  = y + 2 * dyi - 20;
    bool y2ok = (y2 >= 0) && (y2 < Hn);

    int tid = threadIdx.x;
    int w   = tid >> 6;
    int l   = tid & 63;
    int p   = w >> 1;
    int h   = w & 1;
    int g   = l >> 4;
    int m16 = l & 15;

    const size_t chw = (size_t)Hn * Wn;
    const float* pA = in1 + ((size_t)b * Cn) * chw + (size_t)y * Wn;
    const float* pB = in2 + ((size_t)b * Cn) * chw + (size_t)(y2ok ? y2 : 0) * Wn;

    int tm = tid & 63;
    int tg = tid >> 6;
    const int loff = ((tm >> 4) * 4 + tg) * 64 + (tm & 15) * 4;

    f32x4 acc[2][4] = {};
    float ax[8], ay[8], bx[8], by[8];

    auto prefetch = [&](int chunk) {
        size_t base = (size_t)(chunk * KC + 8 * tg) * chw + 2 * tm;
#pragma unroll
        for (int k = 0; k < 8; ++k) {
            float2 tA = *(const float2*)(pA + base + (size_t)k * chw);
            float2 tB = *(const float2*)(pB + base + (size_t)k * chw);
            ax[k] = tA.x; ay[k] = tA.y;
            bx[k] = tB.x; by[k] = tB.y;
        }
        __builtin_amdgcn_sched_barrier(0);
    };
    auto writeout = [&]() {
#pragma unroll
        for (int k = 0; k < 8; ++k)
            asm volatile("" : "+v"(ax[k]), "+v"(ay[k]), "+v"(bx[k]), "+v"(by[k]));
        u32x4 ae, ao, be, bo;
#pragma unroll
        for (int ku = 0; ku < 4; ++ku) {
            ae[ku] = pack_bf16(ax[2 * ku], ax[2 * ku + 1]);
            ao[ku] = pack_bf16(ay[2 * ku], ay[2 * ku + 1]);
            be[ku] = pack_bf16(bx[2 * ku], bx[2 * ku + 1]);
            bo[ku] = pack_bf16(by[2 * ku], by[2 * ku + 1]);
        }
        *(u32x4*)&lds[0][loff] = ae;
        *(u32x4*)&lds[1][loff] = ao;
        *(u32x4*)&lds[2][loff] = be;
        *(u32x4*)&lds[3][loff] = bo;
    };
    auto compute = [&]() {
        const unsigned* Pa = &lds[p][0];
        const unsigned* Pb = &lds[2 + p][0];
        int fo = g * 64 + m16 * 4;
        bf16x8 A0  = *(const bf16x8*)(Pa + (2 * h + 0) * 256 + fo);
        bf16x8 A1  = *(const bf16x8*)(Pa + (2 * h + 1) * 256 + fo);
        bf16x8 Bf0 = *(const bf16x8*)(Pb + 0 * 256 + fo);
        bf16x8 Bf1 = *(const bf16x8*)(Pb + 1 * 256 + fo);
        bf16x8 Bf2 = *(const bf16x8*)(Pb + 2 * 256 + fo);
        bf16x8 Bf3 = *(const bf16x8*)(Pb + 3 * 256 + fo);
        acc[0][0] = __builtin_amdgcn_mfma_f32_16x16x32_bf16(A0, Bf0, acc[0][0], 0, 0, 0);
        acc[0][1] = __builtin_amdgcn_mfma_f32_16x16x32_bf16(A0, Bf1, acc[0][1], 0, 0, 0);
        acc[0][2] = __builtin_amdgcn_mfma_f32_16x16x32_bf16(A0, Bf2, acc[0][2], 0, 0, 0);
        acc[0][3] = __builtin_amdgcn_mfma_f32_16x16x32_bf16(A0, Bf3, acc[0][3], 0, 0, 0);
        acc[1][0] = __builtin_amdgcn_mfma_f32_16x16x32_bf16(A1, Bf0, acc[1][0], 0, 0, 0);
        acc[1][1] = __builtin_amdgcn_mfma_f32_16x16x32_bf16(A1, Bf1, acc[1][1], 0, 0, 0);
        acc[1][2] = __builtin_amdgcn_mfma_f32_16x16x32_bf16(A1, Bf2, acc[1][2], 0, 0, 0);
        acc[1][3] = __builtin_amdgcn_mfma_f32_16x16x32_bf16(A1, Bf3, acc[1][3], 0, 0, 0);
    };

    if (y2ok) {
        prefetch(0);
        for (int it = 0; it < NCH; ++it) {
            writeout();
            lds_barrier();
            if (it + 1 < NCH) prefetch(it + 1);
            compute();
            lds_barrier();
        }
    }

    __syncthreads();
    float* sout = (float*)&lds[0][0];
    for (int i2 = tid; i2 < Wn * JW; i2 += 256) sout[i2] = 0.0f;
    __syncthreads();
    if (y2ok) {
        const float scale = 1.0f / 256.0f;
#pragma unroll
        for (int a = 0; a < 2; ++a)
#pragma unroll
            for (int n = 0; n < 4; ++n)
#pragma unroll
                for (int r = 0; r < 4; ++r) {
                    int xp = (2 * h + a) * 16 + g * 4 + r;
                    int up = n * 16 + m16;
                    int j  = up - xp + 10;
                    if ((unsigned)j < 21u)
                        sout[(2 * xp + p) * JW + j] = acc[a][n][r] * scale;
                }
    }
    __syncthreads();
    unsigned base0 = (unsigned)(((b * (GW * GW) + dyi * GW) * Hn + y) * Wn);
    constexpr unsigned PLANE = (unsigned)(Hn * Wn);
    for (int s = tid; s < GW * Wn; s += 256) {
        int j = s >> 7;
        int x = s & 127;
        out[base0 + (unsigned)j * PLANE + (unsigned)x] = sout[x * JW + j];
    }
}

extern "C" void kernel_launch(void* const* d_in, const int* in_sizes, int n_in,
                              void* d_out, int out_size, void* d_ws, size_t ws_size,
                              hipStream_t stream) {
    const float* in1 = (const float*)d_in[0];
    const float* in2 = (const float*)d_in[1];
    float* out = (float*)d_out;
    size_t need = 2 * TELEMS * sizeof(unsigned);   // 100,663,296 B
    if (ws_size >= need) {
        unsigned* T = (unsigned*)d_ws;
        prepack<<<2 * Bn * Hn * NCH, 256, 0, stream>>>(in1, in2, T);
        corr_fragk<<<NWG, 256, 0, stream>>>(T, T + TELEMS, out);
    } else {
        corr_mfma_fb<<<NWG, 256, 0, stream>>>(in1, in2, out);
    }
}

// Round 28
// 169.390 us; speedup vs baseline: 1.2067x; 1.0518x over previous
//
#include <hip/hip_runtime.h>
#include <hip/hip_bf16.h>

// FlowNetC correlation, round 28: r25 (prepack + barrier-free band MFMA, 172us total)
// with the software pipeline PINNED. r25's VGPR=56 proved the compiler folded the
// next-chunk prefetch (no sched_barrier) -> each wave: issue 5 loads, vmcnt(0), 5
// MFMAs, repeat = ~1KB in flight/wave. r24-r27 showed delivered L2 BW = occupancy x
// per-wave MLP; this doubles per-wave MLP at +~30 VGPR (same occupancy class).
// Change vs r25: sched_barrier(0) after next-chunk load issue, explicit swap.

typedef __attribute__((ext_vector_type(8))) short bf16x8;
typedef __attribute__((ext_vector_type(4))) float f32x4;
typedef __attribute__((ext_vector_type(4))) unsigned u32x4;

constexpr int Bn = 8, Cn = 256, Hn = 96, Wn = 128, GW = 21;
constexpr int KC = 32, NCH = Cn / KC;     // 8 chunks of 32 channels
constexpr int NWG = Bn * Hn * GW;         // 16128, divisible by 8
constexpr int JW = 23;                    // sout pad
constexpr size_t TELEMS = (size_t)Bn * Hn * NCH * 2048;  // 12,582,912 u32 per input

__device__ inline unsigned pack_bf16(float lo, float hi) {
    __hip_bfloat16 l = __float2bfloat16(lo);
    __hip_bfloat16 h = __float2bfloat16(hi);
    unsigned short lu, hu;
    __builtin_memcpy(&lu, &l, 2);
    __builtin_memcpy(&hu, &h, 2);
    return (unsigned)lu | ((unsigned)hu << 16);
}

// ---------------- prepack: f32 -> bf16-pair u32 panels (r24, proven) ----------------
// T[inp][b][y][chunk][par][mt4][kg4][pos16][ku4]; u32 = {bf16(c), bf16(c+1)},
// c = chunk*32 + 8*kg + 2*ku, x = 2*(mt*16+pos)+par.
__global__ __launch_bounds__(256) void prepack(
    const float* __restrict__ in1, const float* __restrict__ in2,
    unsigned* __restrict__ T)
{
    unsigned u = blockIdx.x;
    int ch = u & 7;  u >>= 3;
    int y  = u % 96; u /= 96;
    int b  = u & 7;  u >>= 3;
    const float* src = u ? in2 : in1;

    int t  = threadIdx.x;
    int tm = t & 63;          // x-pair
    int tg = t >> 6;          // kg

    const size_t chw = (size_t)Hn * Wn;
    const float* p = src + ((size_t)(b * Cn + ch * 32 + 8 * tg)) * chw
                         + (size_t)y * Wn + 2 * tm;
    float2 f[8];
#pragma unroll
    for (int k = 0; k < 8; ++k)
        f[k] = *(const float2*)(p + (size_t)k * chw);

    u32x4 ae, ao;
#pragma unroll
    for (int ku = 0; ku < 4; ++ku) {
        ae[ku] = pack_bf16(f[2 * ku].x, f[2 * ku + 1].x);
        ao[ku] = pack_bf16(f[2 * ku].y, f[2 * ku + 1].y);
    }
    unsigned* To = T + u * TELEMS + ((size_t)(b * Hn + y) * NCH + ch) * 2048
                     + ((tm >> 4) * 4 + tg) * 64 + (tm & 15) * 4;
    *(u32x4*)(To)        = ae;    // par 0
    *(u32x4*)(To + 1024) = ao;    // par 1
}

// ---------------- main: barrier-free band-only MFMA, pinned pipeline ----------------
__global__ __launch_bounds__(256) void corr_frag(
    const unsigned* __restrict__ T1, const unsigned* __restrict__ T2,
    float* __restrict__ out)
{
    __shared__ float sout[Wn * JW];   // 11.5 KB, epilogue only

    // r19 L2-locality decode: XCD owns y-band of 12; (b, par, sub, dyi, yw)
    int orig = blockIdx.x;
    int xcd  = orig & 7;
    int i    = orig >> 3;
    int yw   = i % 3;  int t = i / 3;
    int dyi  = t % 21; t /= 21;
    int sub  = t & 1;
    int par  = (t >> 1) & 1;
    int b    = t >> 2;
    int y    = 12 * xcd + par + 2 * (3 * sub + yw);

    int y2  = y + 2 * dyi - 20;
    bool y2ok = (y2 >= 0) && (y2 < Hn);

    int tid = threadIdx.x;
    int w   = tid >> 6;          // wave 0..3
    int l   = tid & 63;
    int p   = w >> 1;            // parity
    int h   = w & 1;             // x-half: mt in {2h, 2h+1}
    int g   = l >> 4;            // k-group
    int m16 = l & 15;

    f32x4 acc[2][4] = {};        // acc[a][n]; only band entries updated

    if (y2ok) {
        const unsigned* pa = T1 + (size_t)(b * Hn + y)  * (NCH * 2048)
                                + p * 1024 + g * 64 + m16 * 4;
        const unsigned* pb = T2 + (size_t)(b * Hn + y2) * (NCH * 2048)
                                + p * 1024 + g * 64 + m16 * 4 + h * 256;

        bf16x8 ca0, ca1, cb0, cb1, cb2;           // current chunk frags
        ca0 = *(const bf16x8*)(pa + (2 * h + 0) * 256);
        ca1 = *(const bf16x8*)(pa + (2 * h + 1) * 256);
        cb0 = *(const bf16x8*)(pb + 0 * 256);
        cb1 = *(const bf16x8*)(pb + 1 * 256);
        cb2 = *(const bf16x8*)(pb + 2 * 256);

        for (int ch = 0; ch < NCH; ++ch) {
            bf16x8 na0, na1, nb0, nb1, nb2;
            if (ch + 1 < NCH) {                   // issue next-chunk loads NOW
                const unsigned* A = pa + (ch + 1) * 2048;
                const unsigned* B = pb + (ch + 1) * 2048;
                na0 = *(const bf16x8*)(A + (2 * h + 0) * 256);
                na1 = *(const bf16x8*)(A + (2 * h + 1) * 256);
                nb0 = *(const bf16x8*)(B + 0 * 256);
                nb1 = *(const bf16x8*)(B + 1 * 256);
                nb2 = *(const bf16x8*)(B + 2 * 256);
            }
            // pin: loads above cannot sink below; MFMAs below cannot hoist above.
            __builtin_amdgcn_sched_barrier(0);
            if (h == 0) {
                // mt=0: nt 0,1; mt=1: nt 0,1,2  (cb_k = B row k)
                acc[0][0] = __builtin_amdgcn_mfma_f32_16x16x32_bf16(ca0, cb0, acc[0][0], 0, 0, 0);
                acc[0][1] = __builtin_amdgcn_mfma_f32_16x16x32_bf16(ca0, cb1, acc[0][1], 0, 0, 0);
                acc[1][0] = __builtin_amdgcn_mfma_f32_16x16x32_bf16(ca1, cb0, acc[1][0], 0, 0, 0);
                acc[1][1] = __builtin_amdgcn_mfma_f32_16x16x32_bf16(ca1, cb1, acc[1][1], 0, 0, 0);
                acc[1][2] = __builtin_amdgcn_mfma_f32_16x16x32_bf16(ca1, cb2, acc[1][2], 0, 0, 0);
            } else {
                // mt=2: nt 1,2,3 (cb_k = B row 1+k); mt=3: nt 2,3
                acc[0][1] = __builtin_amdgcn_mfma_f32_16x16x32_bf16(ca0, cb0, acc[0][1], 0, 0, 0);
                acc[0][2] = __builtin_amdgcn_mfma_f32_16x16x32_bf16(ca0, cb1, acc[0][2], 0, 0, 0);
                acc[0][3] = __builtin_amdgcn_mfma_f32_16x16x32_bf16(ca0, cb2, acc[0][3], 0, 0, 0);
                acc[1][2] = __builtin_amdgcn_mfma_f32_16x16x32_bf16(ca1, cb1, acc[1][2], 0, 0, 0);
                acc[1][3] = __builtin_amdgcn_mfma_f32_16x16x32_bf16(ca1, cb2, acc[1][3], 0, 0, 0);
            }
            ca0 = na0; ca1 = na1;
            cb0 = nb0; cb1 = nb1; cb2 = nb2;
        }
    }

    // ---- epilogue: LDS-transposed, coalesced stores (r24/r25, proven) ----
    for (int i2 = tid; i2 < Wn * JW; i2 += 256) sout[i2] = 0.0f;
    __syncthreads();                       // zeros visible

    if (y2ok) {
        const float scale = 1.0f / 256.0f;
#pragma unroll
        for (int a = 0; a < 2; ++a)
#pragma unroll
            for (int n = 0; n < 4; ++n)
#pragma unroll
                for (int r = 0; r < 4; ++r) {
                    int xp = (2 * h + a) * 16 + g * 4 + r;   // x' (C/D row)
                    int up = n * 16 + m16;                   // u' (C/D col)
                    int j  = up - xp + 10;
                    if ((unsigned)j < 21u)
                        sout[(2 * xp + p) * JW + j] = acc[a][n][r] * scale;
                }
    }
    __syncthreads();                       // scatter visible

    unsigned base0 = (unsigned)(((b * (GW * GW) + dyi * GW) * Hn + y) * Wn);
    constexpr unsigned PLANE = (unsigned)(Hn * Wn);
    for (int s = tid; s < GW * Wn; s += 256) {
        int j = s >> 7;
        int x = s & 127;
        out[base0 + (unsigned)j * PLANE + (unsigned)x] = sout[x * JW + j];
    }
}

// ---------------- fallback (r21, proven): used if ws too small ----------------
__device__ inline void lds_barrier() {
    asm volatile("s_waitcnt lgkmcnt(0)" ::: "memory");
    __builtin_amdgcn_s_barrier();
    __builtin_amdgcn_sched_barrier(0);
}

__global__ __launch_bounds__(256) void corr_mfma_fb(
    const float* __restrict__ in1, const float* __restrict__ in2,
    float* __restrict__ out)
{
    __shared__ unsigned lds[4][1024];
    int orig = blockIdx.x;
    int xcd  = orig & 7;
    int i    = orig >> 3;
    int yw   = i % 3;  int t = i / 3;
    int dyi  = t % 21; t /= 21;
    int sub  = t & 1;
    int par  = (t >> 1) & 1;
    int b    = t >> 2;
    int y    = 12 * xcd + par + 2 * (3 * sub + yw);
    int y2  = y + 2 * dyi - 20;
    bool y2ok = (y2 >= 0) && (y2 < Hn);

    int tid = threadIdx.x;
    int w   = tid >> 6;
    int l   = tid & 63;
    int p   = w >> 1;
    int h   = w & 1;
    int g   = l >> 4;
    int m16 = l & 15;

    const size_t chw = (size_t)Hn * Wn;
    const float* pA = in1 + ((size_t)b * Cn) * chw + (size_t)y * Wn;
    const float* pB = in2 + ((size_t)b * Cn) * chw + (size_t)(y2ok ? y2 : 0) * Wn;

    int tm = tid & 63;
    int tg = tid >> 6;
    const int loff = ((tm >> 4) * 4 + tg) * 64 + (tm & 15) * 4;

    f32x4 acc[2][4] = {};
    float ax[8], ay[8], bx[8], by[8];

    auto prefetch = [&](int chunk) {
        size_t base = (size_t)(chunk * KC + 8 * tg) * chw + 2 * tm;
#pragma unroll
        for (int k = 0; k < 8; ++k) {
            float2 tA = *(const float2*)(pA + base + (size_t)k * chw);
            float2 tB = *(const float2*)(pB + base + (size_t)k * chw);
            ax[k] = tA.x; ay[k] = tA.y;
            bx[k] = tB.x; by[k] = tB.y;
        }
        __builtin_amdgcn_sched_barrier(0);
    };
    auto writeout = [&]() {
#pragma unroll
        for (int k = 0; k < 8; ++k)
            asm volatile("" : "+v"(ax[k]), "+v"(ay[k]), "+v"(bx[k]), "+v"(by[k]));
        u32x4 ae, ao, be, bo;
#pragma unroll
        for (int ku = 0; ku < 4; ++ku) {
            ae[ku] = pack_bf16(ax[2 * ku], ax[2 * ku + 1]);
            ao[ku] = pack_bf16(ay[2 * ku], ay[2 * ku + 1]);
            be[ku] = pack_bf16(bx[2 * ku], bx[2 * ku + 1]);
            bo[ku] = pack_bf16(by[2 * ku], by[2 * ku + 1]);
        }
        *(u32x4*)&lds[0][loff] = ae;
        *(u32x4*)&lds[1][loff] = ao;
        *(u32x4*)&lds[2][loff] = be;
        *(u32x4*)&lds[3][loff] = bo;
    };
    auto compute = [&]() {
        const unsigned* Pa = &lds[p][0];
        const unsigned* Pb = &lds[2 + p][0];
        int fo = g * 64 + m16 * 4;
        bf16x8 A0  = *(const bf16x8*)(Pa + (2 * h + 0) * 256 + fo);
        bf16x8 A1  = *(const bf16x8*)(Pa + (2 * h + 1) * 256 + fo);
        bf16x8 Bf0 = *(const bf16x8*)(Pb + 0 * 256 + fo);
        bf16x8 Bf1 = *(const bf16x8*)(Pb + 1 * 256 + fo);
        bf16x8 Bf2 = *(const bf16x8*)(Pb + 2 * 256 + fo);
        bf16x8 Bf3 = *(const bf16x8*)(Pb + 3 * 256 + fo);
        acc[0][0] = __builtin_amdgcn_mfma_f32_16x16x32_bf16(A0, Bf0, acc[0][0], 0, 0, 0);
        acc[0][1] = __builtin_amdgcn_mfma_f32_16x16x32_bf16(A0, Bf1, acc[0][1], 0, 0, 0);
        acc[0][2] = __builtin_amdgcn_mfma_f32_16x16x32_bf16(A0, Bf2, acc[0][2], 0, 0, 0);
        acc[0][3] = __builtin_amdgcn_mfma_f32_16x16x32_bf16(A0, Bf3, acc[0][3], 0, 0, 0);
        acc[1][0] = __builtin_amdgcn_mfma_f32_16x16x32_bf16(A1, Bf0, acc[1][0], 0, 0, 0);
        acc[1][1] = __builtin_amdgcn_mfma_f32_16x16x32_bf16(A1, Bf1, acc[1][1], 0, 0, 0);
        acc[1][2] = __builtin_amdgcn_mfma_f32_16x16x32_bf16(A1, Bf2, acc[1][2], 0, 0, 0);
        acc[1][3] = __builtin_amdgcn_mfma_f32_16x16x32_bf16(A1, Bf3, acc[1][3], 0, 0, 0);
    };

    if (y2ok) {
        prefetch(0);
        for (int it = 0; it < NCH; ++it) {
            writeout();
            lds_barrier();
            if (it + 1 < NCH) prefetch(it + 1);
            compute();
            lds_barrier();
        }
    }

    __syncthreads();
    float* sout = (float*)&lds[0][0];
    for (int i2 = tid; i2 < Wn * JW; i2 += 256) sout[i2] = 0.0f;
    __syncthreads();
    if (y2ok) {
        const float scale = 1.0f / 256.0f;
#pragma unroll
        for (int a = 0; a < 2; ++a)
#pragma unroll
            for (int n = 0; n < 4; ++n)
#pragma unroll
                for (int r = 0; r < 4; ++r) {
                    int xp = (2 * h + a) * 16 + g * 4 + r;
                    int up = n * 16 + m16;
                    int j  = up - xp + 10;
                    if ((unsigned)j < 21u)
                        sout[(2 * xp + p) * JW + j] = acc[a][n][r] * scale;
                }
    }
    __syncthreads();
    unsigned base0 = (unsigned)(((b * (GW * GW) + dyi * GW) * Hn + y) * Wn);
    constexpr unsigned PLANE = (unsigned)(Hn * Wn);
    for (int s = tid; s < GW * Wn; s += 256) {
        int j = s >> 7;
        int x = s & 127;
        out[base0 + (unsigned)j * PLANE + (unsigned)x] = sout[x * JW + j];
    }
}

extern "C" void kernel_launch(void* const* d_in, const int* in_sizes, int n_in,
                              void* d_out, int out_size, void* d_ws, size_t ws_size,
                              hipStream_t stream) {
    const float* in1 = (const float*)d_in[0];
    const float* in2 = (const float*)d_in[1];
    float* out = (float*)d_out;
    size_t need = 2 * TELEMS * sizeof(unsigned);   // 100,663,296 B
    if (ws_size >= need) {
        unsigned* T = (unsigned*)d_ws;
        prepack<<<2 * Bn * Hn * NCH, 256, 0, stream>>>(in1, in2, T);
        corr_frag<<<NWG, 256, 0, stream>>>(T, T + TELEMS, out);
    } else {
        corr_mfma_fb<<<NWG, 256, 0, stream>>>(in1, in2, out);
    }
}

// Round 29
// 164.651 us; speedup vs baseline: 1.2414x; 1.0288x over previous
//
#include <hip/hip_runtime.h>
#include <hip/hip_bf16.h>

// FlowNetC correlation, round 29: r25/r28 base + DEPTH-3 register pipeline.
// r28 proved depth-1 was already live (VGPR 56 = 2x5 frag sets, acc in AGPR).
// Timing math: ~2000 cyc/iteration => loads are L3-class latency (per-XCD working
// set 12.6MB >> 4MB L2; B rows span y+-20 across XCD bands). Fix: 3-set rotation,
// ISSUE(k+3) after COMPUTE(k), fully peeled (all reg indices compile-time) ->
// >=10 loads in flight per wave instead of 5.

typedef __attribute__((ext_vector_type(8))) short bf16x8;
typedef __attribute__((ext_vector_type(4))) float f32x4;
typedef __attribute__((ext_vector_type(4))) unsigned u32x4;

constexpr int Bn = 8, Cn = 256, Hn = 96, Wn = 128, GW = 21;
constexpr int KC = 32, NCH = Cn / KC;     // 8 chunks of 32 channels
constexpr int NWG = Bn * Hn * GW;         // 16128, divisible by 8
constexpr int JW = 23;                    // sout pad
constexpr size_t TELEMS = (size_t)Bn * Hn * NCH * 2048;  // 12,582,912 u32 per input

__device__ inline unsigned pack_bf16(float lo, float hi) {
    __hip_bfloat16 l = __float2bfloat16(lo);
    __hip_bfloat16 h = __float2bfloat16(hi);
    unsigned short lu, hu;
    __builtin_memcpy(&lu, &l, 2);
    __builtin_memcpy(&hu, &h, 2);
    return (unsigned)lu | ((unsigned)hu << 16);
}

// ---------------- prepack: f32 -> bf16-pair u32 panels (r24, proven) ----------------
__global__ __launch_bounds__(256) void prepack(
    const float* __restrict__ in1, const float* __restrict__ in2,
    unsigned* __restrict__ T)
{
    unsigned u = blockIdx.x;
    int ch = u & 7;  u >>= 3;
    int y  = u % 96; u /= 96;
    int b  = u & 7;  u >>= 3;
    const float* src = u ? in2 : in1;

    int t  = threadIdx.x;
    int tm = t & 63;          // x-pair
    int tg = t >> 6;          // kg

    const size_t chw = (size_t)Hn * Wn;
    const float* p = src + ((size_t)(b * Cn + ch * 32 + 8 * tg)) * chw
                         + (size_t)y * Wn + 2 * tm;
    float2 f[8];
#pragma unroll
    for (int k = 0; k < 8; ++k)
        f[k] = *(const float2*)(p + (size_t)k * chw);

    u32x4 ae, ao;
#pragma unroll
    for (int ku = 0; ku < 4; ++ku) {
        ae[ku] = pack_bf16(f[2 * ku].x, f[2 * ku + 1].x);
        ao[ku] = pack_bf16(f[2 * ku].y, f[2 * ku + 1].y);
    }
    unsigned* To = T + u * TELEMS + ((size_t)(b * Hn + y) * NCH + ch) * 2048
                     + ((tm >> 4) * 4 + tg) * 64 + (tm & 15) * 4;
    *(u32x4*)(To)        = ae;    // par 0
    *(u32x4*)(To + 1024) = ao;    // par 1
}

// ---------------- main: barrier-free band MFMA, depth-3 pipeline ----------------
__global__ __launch_bounds__(256) void corr_frag(
    const unsigned* __restrict__ T1, const unsigned* __restrict__ T2,
    float* __restrict__ out)
{
    __shared__ float sout[Wn * JW];   // 11.5 KB, epilogue only

    // r19 L2-locality decode
    int orig = blockIdx.x;
    int xcd  = orig & 7;
    int i    = orig >> 3;
    int yw   = i % 3;  int t = i / 3;
    int dyi  = t % 21; t /= 21;
    int sub  = t & 1;
    int par  = (t >> 1) & 1;
    int b    = t >> 2;
    int y    = 12 * xcd + par + 2 * (3 * sub + yw);

    int y2  = y + 2 * dyi - 20;
    bool y2ok = (y2 >= 0) && (y2 < Hn);

    int tid = threadIdx.x;
    int w   = tid >> 6;          // wave 0..3
    int l   = tid & 63;
    int p   = w >> 1;            // parity
    int h   = w & 1;             // x-half: mt in {2h, 2h+1}
    int g   = l >> 4;            // k-group
    int m16 = l & 15;

    f32x4 acc[2][4] = {};        // acc[a][n]; only band entries updated

    if (y2ok) {
        const unsigned* pa = T1 + (size_t)(b * Hn + y)  * (NCH * 2048)
                                + p * 1024 + g * 64 + m16 * 4;
        const unsigned* pb = T2 + (size_t)(b * Hn + y2) * (NCH * 2048)
                                + p * 1024 + g * 64 + m16 * 4 + h * 256;

        // 3-set rotation; all indices compile-time after expansion (rule #20)
        bf16x8 A0[3], A1[3], B0[3], B1[3], B2[3];

#define ISSUE(k) {                                                          \
            const unsigned* A = pa + (k) * 2048;                            \
            const unsigned* B = pb + (k) * 2048;                            \
            A0[(k) % 3] = *(const bf16x8*)(A + (2 * h + 0) * 256);          \
            A1[(k) % 3] = *(const bf16x8*)(A + (2 * h + 1) * 256);          \
            B0[(k) % 3] = *(const bf16x8*)(B + 0 * 256);                    \
            B1[(k) % 3] = *(const bf16x8*)(B + 1 * 256);                    \
            B2[(k) % 3] = *(const bf16x8*)(B + 2 * 256);                    \
        }
#define COMPUTE(k) {                                                        \
            __builtin_amdgcn_sched_barrier(0);                              \
            bf16x8 a0 = A0[(k) % 3], a1 = A1[(k) % 3];                      \
            bf16x8 b0 = B0[(k) % 3], b1 = B1[(k) % 3], b2 = B2[(k) % 3];    \
            if (h == 0) {                                                   \
                acc[0][0] = __builtin_amdgcn_mfma_f32_16x16x32_bf16(a0, b0, acc[0][0], 0, 0, 0); \
                acc[0][1] = __builtin_amdgcn_mfma_f32_16x16x32_bf16(a0, b1, acc[0][1], 0, 0, 0); \
                acc[1][0] = __builtin_amdgcn_mfma_f32_16x16x32_bf16(a1, b0, acc[1][0], 0, 0, 0); \
                acc[1][1] = __builtin_amdgcn_mfma_f32_16x16x32_bf16(a1, b1, acc[1][1], 0, 0, 0); \
                acc[1][2] = __builtin_amdgcn_mfma_f32_16x16x32_bf16(a1, b2, acc[1][2], 0, 0, 0); \
            } else {                                                        \
                acc[0][1] = __builtin_amdgcn_mfma_f32_16x16x32_bf16(a0, b0, acc[0][1], 0, 0, 0); \
                acc[0][2] = __builtin_amdgcn_mfma_f32_16x16x32_bf16(a0, b1, acc[0][2], 0, 0, 0); \
                acc[0][3] = __builtin_amdgcn_mfma_f32_16x16x32_bf16(a0, b2, acc[0][3], 0, 0, 0); \
                acc[1][2] = __builtin_amdgcn_mfma_f32_16x16x32_bf16(a1, b1, acc[1][2], 0, 0, 0); \
                acc[1][3] = __builtin_amdgcn_mfma_f32_16x16x32_bf16(a1, b2, acc[1][3], 0, 0, 0); \
            }                                                               \
        }

        ISSUE(0); ISSUE(1); ISSUE(2);
        COMPUTE(0); ISSUE(3);
        COMPUTE(1); ISSUE(4);
        COMPUTE(2); ISSUE(5);
        COMPUTE(3); ISSUE(6);
        COMPUTE(4); ISSUE(7);
        COMPUTE(5);
        COMPUTE(6);
        COMPUTE(7);
#undef ISSUE
#undef COMPUTE
    }

    // ---- epilogue: LDS-transposed, coalesced stores (r24/r25, proven) ----
    for (int i2 = tid; i2 < Wn * JW; i2 += 256) sout[i2] = 0.0f;
    __syncthreads();                       // zeros visible

    if (y2ok) {
        const float scale = 1.0f / 256.0f;
#pragma unroll
        for (int a = 0; a < 2; ++a)
#pragma unroll
            for (int n = 0; n < 4; ++n)
#pragma unroll
                for (int r = 0; r < 4; ++r) {
                    int xp = (2 * h + a) * 16 + g * 4 + r;   // x' (C/D row)
                    int up = n * 16 + m16;                   // u' (C/D col)
                    int j  = up - xp + 10;
                    if ((unsigned)j < 21u)
                        sout[(2 * xp + p) * JW + j] = acc[a][n][r] * scale;
                }
    }
    __syncthreads();                       // scatter visible

    unsigned base0 = (unsigned)(((b * (GW * GW) + dyi * GW) * Hn + y) * Wn);
    constexpr unsigned PLANE = (unsigned)(Hn * Wn);
    for (int s = tid; s < GW * Wn; s += 256) {
        int j = s >> 7;
        int x = s & 127;
        out[base0 + (unsigned)j * PLANE + (unsigned)x] = sout[x * JW + j];
    }
}

// ---------------- fallback (r21, proven): used if ws too small ----------------
__device__ inline void lds_barrier() {
    asm volatile("s_waitcnt lgkmcnt(0)" ::: "memory");
    __builtin_amdgcn_s_barrier();
    __builtin_amdgcn_sched_barrier(0);
}

__global__ __launch_bounds__(256) void corr_mfma_fb(
    const float* __restrict__ in1, const float* __restrict__ in2,
    float* __restrict__ out)
{
    __shared__ unsigned lds[4][1024];
    int orig = blockIdx.x;
    int xcd  = orig & 7;
    int i    = orig >> 3;
    int yw   = i % 3;  int t = i / 3;
    int dyi  = t % 21; t /= 21;
    int sub  = t & 1;
    int par  = (t >> 1) & 1;
    int b    = t >> 2;
    int y    = 12 * xcd + par + 2 * (3 * sub + yw);
    int y2  = y + 2 * dyi - 20;
    bool y2ok = (y2 >= 0) && (y2 < Hn);

    int tid = threadIdx.x;
    int w   = tid >> 6;
    int l   = tid & 63;
    int p   = w >> 1;
    int h   = w & 1;
    int g   = l >> 4;
    int m16 = l & 15;

    const size_t chw = (size_t)Hn * Wn;
    const float* pA = in1 + ((size_t)b * Cn) * chw + (size_t)y * Wn;
    const float* pB = in2 + ((size_t)b * Cn) * chw + (size_t)(y2ok ? y2 : 0) * Wn;

    int tm = tid & 63;
    int tg = tid >> 6;
    const int loff = ((tm >> 4) * 4 + tg) * 64 + (tm & 15) * 4;

    f32x4 acc[2][4] = {};
    float ax[8], ay[8], bx[8], by[8];

    auto prefetch = [&](int chunk) {
        size_t base = (size_t)(chunk * KC + 8 * tg) * chw + 2 * tm;
#pragma unroll
        for (int k = 0; k < 8; ++k) {
            float2 tA = *(const float2*)(pA + base + (size_t)k * chw);
            float2 tB = *(const float2*)(pB + base + (size_t)k * chw);
            ax[k] = tA.x; ay[k] = tA.y;
            bx[k] = tB.x; by[k] = tB.y;
        }
        __builtin_amdgcn_sched_barrier(0);
    };
    auto writeout = [&]() {
#pragma unroll
        for (int k = 0; k < 8; ++k)
            asm volatile("" : "+v"(ax[k]), "+v"(ay[k]), "+v"(bx[k]), "+v"(by[k]));
        u32x4 ae, ao, be, bo;
#pragma unroll
        for (int ku = 0; ku < 4; ++ku) {
            ae[ku] = pack_bf16(ax[2 * ku], ax[2 * ku + 1]);
            ao[ku] = pack_bf16(ay[2 * ku], ay[2 * ku + 1]);
            be[ku] = pack_bf16(bx[2 * ku], bx[2 * ku + 1]);
            bo[ku] = pack_bf16(by[2 * ku], by[2 * ku + 1]);
        }
        *(u32x4*)&lds[0][loff] = ae;
        *(u32x4*)&lds[1][loff] = ao;
        *(u32x4*)&lds[2][loff] = be;
        *(u32x4*)&lds[3][loff] = bo;
    };
    auto compute = [&]() {
        const unsigned* Pa = &lds[p][0];
        const unsigned* Pb = &lds[2 + p][0];
        int fo = g * 64 + m16 * 4;
        bf16x8 A0  = *(const bf16x8*)(Pa + (2 * h + 0) * 256 + fo);
        bf16x8 A1  = *(const bf16x8*)(Pa + (2 * h + 1) * 256 + fo);
        bf16x8 Bf0 = *(const bf16x8*)(Pb + 0 * 256 + fo);
        bf16x8 Bf1 = *(const bf16x8*)(Pb + 1 * 256 + fo);
        bf16x8 Bf2 = *(const bf16x8*)(Pb + 2 * 256 + fo);
        bf16x8 Bf3 = *(const bf16x8*)(Pb + 3 * 256 + fo);
        acc[0][0] = __builtin_amdgcn_mfma_f32_16x16x32_bf16(A0, Bf0, acc[0][0], 0, 0, 0);
        acc[0][1] = __builtin_amdgcn_mfma_f32_16x16x32_bf16(A0, Bf1, acc[0][1], 0, 0, 0);
        acc[0][2] = __builtin_amdgcn_mfma_f32_16x16x32_bf16(A0, Bf2, acc[0][2], 0, 0, 0);
        acc[0][3] = __builtin_amdgcn_mfma_f32_16x16x32_bf16(A0, Bf3, acc[0][3], 0, 0, 0);
        acc[1][0] = __builtin_amdgcn_mfma_f32_16x16x32_bf16(A1, Bf0, acc[1][0], 0, 0, 0);
        acc[1][1] = __builtin_amdgcn_mfma_f32_16x16x32_bf16(A1, Bf1, acc[1][1], 0, 0, 0);
        acc[1][2] = __builtin_amdgcn_mfma_f32_16x16x32_bf16(A1, Bf2, acc[1][2], 0, 0, 0);
        acc[1][3] = __builtin_amdgcn_mfma_f32_16x16x32_bf16(A1, Bf3, acc[1][3], 0, 0, 0);
    };

    if (y2ok) {
        prefetch(0);
        for (int it = 0; it < NCH; ++it) {
            writeout();
            lds_barrier();
            if (it + 1 < NCH) prefetch(it + 1);
            compute();
            lds_barrier();
        }
    }

    __syncthreads();
    float* sout = (float*)&lds[0][0];
    for (int i2 = tid; i2 < Wn * JW; i2 += 256) sout[i2] = 0.0f;
    __syncthreads();
    if (y2ok) {
        const float scale = 1.0f / 256.0f;
#pragma unroll
        for (int a = 0; a < 2; ++a)
#pragma unroll
            for (int n = 0; n < 4; ++n)
#pragma unroll
                for (int r = 0; r < 4; ++r) {
                    int xp = (2 * h + a) * 16 + g * 4 + r;
                    int up = n * 16 + m16;
                    int j  = up - xp + 10;
                    if ((unsigned)j < 21u)
                        sout[(2 * xp + p) * JW + j] = acc[a][n][r] * scale;
                }
    }
    __syncthreads();
    unsigned base0 = (unsigned)(((b * (GW * GW) + dyi * GW) * Hn + y) * Wn);
    constexpr unsigned PLANE = (unsigned)(Hn * Wn);
    for (int s = tid; s < GW * Wn; s += 256) {
        int j = s >> 7;
        int x = s & 127;
        out[base0 + (unsigned)j * PLANE + (unsigned)x] = sout[x * JW + j];
    }
}

extern "C" void kernel_launch(void* const* d_in, const int* in_sizes, int n_in,
                              void* d_out, int out_size, void* d_ws, size_t ws_size,
                              hipStream_t stream) {
    const float* in1 = (const float*)d_in[0];
    const float* in2 = (const float*)d_in[1];
    float* out = (float*)d_out;
    size_t need = 2 * TELEMS * sizeof(unsigned);   // 100,663,296 B
    if (ws_size >= need) {
        unsigned* T = (unsigned*)d_ws;
        prepack<<<2 * Bn * Hn * NCH, 256, 0, stream>>>(in1, in2, T);
        corr_frag<<<NWG, 256, 0, stream>>>(T, T + TELEMS, out);
    } else {
        corr_mfma_fb<<<NWG, 256, 0, stream>>>(in1, in2, out);
    }
}